// Round 5
// baseline (10259.380 us; speedup 1.0000x reference)
//
#include <hip/hip_runtime.h>
#include <stdint.h>

#define Bn 128
#define Tn 256
#define En 300
#define Hn 1024
#define PADIDX 1
// scan: G=4 batch-groups x P=64 unit-blocks = 256 blocks, 128 threads (2 waves)

typedef short s16x8 __attribute__((ext_vector_type(8)));
typedef float f32x4 __attribute__((ext_vector_type(4)));
typedef unsigned int u32;
typedef u32 u32x4 __attribute__((ext_vector_type(4)));
typedef unsigned long long u64;

#define LDQ32(p) __hip_atomic_load((p), __ATOMIC_RELAXED, __HIP_MEMORY_SCOPE_SYSTEM)
#define ST32(p, v) __hip_atomic_store((p), (v), __ATOMIC_RELAXED, __HIP_MEMORY_SCOPE_SYSTEM)

__device__ __forceinline__ unsigned short f2bf(float f) {
  u32 u = __builtin_bit_cast(u32, f);
  u32 r = (u + 0x7fffu + ((u >> 16) & 1u)) >> 16;  // RNE
  return (unsigned short)r;
}
__device__ __forceinline__ float bf2f(unsigned short h) {
  u32 u = ((u32)h) << 16;
  return __builtin_bit_cast(float, u);
}
__device__ __forceinline__ float sigmoidf_(float x) { return 1.f / (1.f + __expf(-x)); }
__device__ __forceinline__ float tanhf_(float x) { return 1.f - 2.f / (__expf(2.f * x) + 1.f); }

// coherent (sc0 sc1 -> L3) and cached 16B loads; results NOT valid until manual s_waitcnt
__device__ __forceinline__ u32x4 ldg_sc_x4(const u32* p) {
  u32x4 r;
  asm volatile("global_load_dwordx4 %0, %1, off sc0 sc1" : "=v"(r) : "v"(p));
  return r;
}
__device__ __forceinline__ u32x4 ldg_x4(const void* p) {
  u32x4 r;
  asm volatile("global_load_dwordx4 %0, %1, off" : "=v"(r) : "v"(p));
  return r;
}
#define WAITV24 do { asm volatile("s_waitcnt vmcnt(24)" ::: "memory"); \
                     __builtin_amdgcn_sched_barrier(0); } while (0)
#define WAITV0  do { asm volatile("s_waitcnt vmcnt(0)" ::: "memory");  \
                     __builtin_amdgcn_sched_barrier(0); } while (0)

// ---------------- K0: lengths -> tstar / padflag ----------------
__global__ void prep_kernel(const int* __restrict__ x, int* __restrict__ tstar,
                            int* __restrict__ padflag) {
  int b = threadIdx.x;
  if (b < Bn) {
    int len = 0;
    for (int t = 0; t < Tn; ++t) len += (x[b * Tn + t] != PADIDX) ? 1 : 0;
    int ts = (len > 0) ? (len - 1) : (Tn - 1);  // jax wraps index -1
    tstar[b] = ts;
    padflag[b] = (x[b * Tn + ts] == PADIDX) ? 1 : 0;
  }
}

// ---------------- K1: embedding gather into A-fragment-linear layout ----------
// inp2[((t*8 + rg)*10 + ks)*64 + l][8] ; rg = g*2+wv ; b = rg*16+(l&15) ;
// k = ks*32 + (l>>4)*8 + jj ; zero-padded past 300.
__global__ void gather2_kernel(const int* __restrict__ x, const float* __restrict__ embed,
                               unsigned short* __restrict__ inp2) {
  int idx = blockIdx.x * 256 + threadIdx.x;  // total 256*8*10*512 = 10,485,760
  int jj = idx & 7;
  int tmp = idx >> 3;
  int l = tmp & 63; tmp >>= 6;
  int ks = tmp % 10; tmp /= 10;
  int rg = tmp & 7;
  int t = tmp >> 3;
  int b = rg * 16 + (l & 15);
  int k = ks * 32 + (l >> 4) * 8 + jj;
  int tok = x[b * Tn + t];
  float v = (k < En) ? embed[(size_t)tok * En + k] : 0.f;
  inp2[idx] = f2bf(v);
}

// ---------------- K2: W_ih -> bf16, B-fragment-linear --------------------------
// wih2[((gg*64+j)*10 + ks)*64 + l][8]; row = gg*1024 + j*16 + (l&15); k as above
__global__ void wih2_kernel(const float* __restrict__ Wih, unsigned short* __restrict__ wih2) {
  int idx = blockIdx.x * 256 + threadIdx.x;  // total 256*10*512 = 1,310,720
  int jj = idx & 7;
  int tmp = idx >> 3;
  int l = tmp & 63; tmp >>= 6;
  int ks = tmp % 10; tmp /= 10;     // tmp = gg*64 + j
  int gg = tmp >> 6, j = tmp & 63;
  int row = gg * Hn + j * 16 + (l & 15);
  int k = ks * 32 + (l >> 4) * 8 + jj;
  float v = (k < En) ? Wih[(size_t)row * En + k] : 0.f;
  wih2[idx] = f2bf(v);
}

// ---------------- K3: W_hh lo residual -> bf16, B-fragment-linear --------------
__global__ void wlo2_kernel(const float* __restrict__ Whh, unsigned short* __restrict__ wlo2) {
  int idx = blockIdx.x * 256 + threadIdx.x;  // total 256*32*512 = 4,194,304
  int jj = idx & 7;
  int tmp = idx >> 3;
  int l = tmp & 63; tmp >>= 6;
  int ks = tmp & 31; tmp >>= 5;     // tmp = gg*64 + j
  int gg = tmp >> 6, j = tmp & 63;
  int row = gg * Hn + j * 16 + (l & 15);
  int k = ks * 32 + (l >> 4) * 8 + jj;
  float w = Whh[(size_t)row * Hn + k];
  unsigned short hi = f2bf(w);
  wlo2[idx] = f2bf(w - bf2f(hi));
}

// ---------------- K4: persistent LSTM scan ----------------
// 256 blocks x 128 thr. bid = g*64 + j  (g: batch-group of 32, j: 16 hidden units).
// bid%8 == j%8 -> same-j blocks co-locate per XCD (perf-only): shared L2 wlo slice.
// LDS: W_hh hi (64 rows x 1024, swizzled) = 128 KB. W_hh lo streamed from L2.
// Tiles = gates: acc[gg] holds gate gg for (16 units x 16 batches) -> no shfl mixing.
// h packed u32 (hi | lo<<16) at L3 via sc0sc1; sync = 1 flag/block + ballot poll.
__global__ __launch_bounds__(128, 1) void lstm_scan(
    const float* __restrict__ Whh, const unsigned short* __restrict__ wih2,
    const unsigned short* __restrict__ wlo2, const float* __restrict__ bih,
    const float* __restrict__ bhh, const unsigned short* __restrict__ inp2,
    const int* __restrict__ tstar, const int* __restrict__ padflag,
    u32* __restrict__ h_pk, float* __restrict__ hsel, u32* __restrict__ flags) {
  __shared__ unsigned short lds_hi[64 * 1024];  // 128 KB
  __shared__ u32 cnt;

  const int bid = blockIdx.x;
  const int g = bid >> 6, j = bid & 63;
  const int u0 = j * 16;
  const int tid = threadIdx.x;
  if (tid == 0) cnt = 0u;

  // fill W_hh hi into LDS (row cc = gg*16 + usub, XOR-swizzled)
  for (int i = tid; i < 64 * 1024; i += 128) {
    int cc = i >> 10, k = i & 1023;
    float w = Whh[(size_t)((cc >> 4) * Hn + u0 + (cc & 15)) * Hn + k];
    u32 byte = ((u32)(cc * 2048 + k * 2)) ^ (((u32)(cc & 7)) << 4);
    lds_hi[byte >> 1] = f2bf(w);
  }
  __syncthreads();

  const int wv = tid >> 6, l = tid & 63;
  const int lr = l & 15, lq = l >> 4;
  const int b0w = g * 32 + wv * 16;
  const u32 swz = ((u32)(lr & 7)) << 4;

  float bias[4];
#pragma unroll
  for (int gg = 0; gg < 4; ++gg) {
    int col = gg * Hn + u0 + lr;
    bias[gg] = bih[col] + bhh[col];
  }
  int tsr[4], pfr[4];
#pragma unroll
  for (int r = 0; r < 4; ++r) {
    int b = b0w + lq * 4 + r;
    tsr[r] = tstar[b];
    pfr[r] = padflag[b];
  }
  float creg[4] = {0.f, 0.f, 0.f, 0.f};

  const unsigned short* wihB = wih2 + (size_t)j * 5120 + l * 8;   // + gg*327680 + ks*512
  const unsigned short* wloB = wlo2 + (size_t)j * 16384 + l * 8;  // + gg*1048576 + ks*512
  u32* const fg = flags + (g << 6);

  u32x4 qa[2][4][2];  // h prefetch (2 chunks x 4 ks x 32B)
  u32x4 qb[2][4][4];  // W-lo prefetch (2 chunks x 4 ks x 4 gates)

#define ISSUE_A(BUF, C)                                                          \
  _Pragma("unroll") for (int ii = 0; ii < 4; ++ii) {                             \
    const u32* p = hbase + ((C)*4 + ii) * 32;                                    \
    qa[BUF][ii][0] = ldg_sc_x4(p);                                               \
    qa[BUF][ii][1] = ldg_sc_x4(p + 4);                                           \
  }
#define ISSUE_BL(BUF, C)                                                         \
  _Pragma("unroll") for (int ii = 0; ii < 4; ++ii)                               \
    _Pragma("unroll") for (int gg = 0; gg < 4; ++gg)                             \
      qb[BUF][ii][gg] =                                                          \
          ldg_x4(wloB + (size_t)gg * 1048576 + ((C)*4 + ii) * 512);
#define BODY_(BUF, C)                                                            \
  _Pragma("unroll") for (int ii = 0; ii < 4; ++ii) {                             \
    int ks = (C)*4 + ii;                                                         \
    u32x4 q0 = qa[BUF][ii][0], q1 = qa[BUF][ii][1];                              \
    u32x4 vh, vl;                                                                \
    vh[0] = __builtin_amdgcn_perm(q0[1], q0[0], 0x05040100u);                    \
    vh[1] = __builtin_amdgcn_perm(q0[3], q0[2], 0x05040100u);                    \
    vh[2] = __builtin_amdgcn_perm(q1[1], q1[0], 0x05040100u);                    \
    vh[3] = __builtin_amdgcn_perm(q1[3], q1[2], 0x05040100u);                    \
    vl[0] = __builtin_amdgcn_perm(q0[1], q0[0], 0x07060302u);                    \
    vl[1] = __builtin_amdgcn_perm(q0[3], q0[2], 0x07060302u);                    \
    vl[2] = __builtin_amdgcn_perm(q1[1], q1[0], 0x07060302u);                    \
    vl[3] = __builtin_amdgcn_perm(q1[3], q1[2], 0x07060302u);                    \
    s16x8 ahi = __builtin_bit_cast(s16x8, vh);                                   \
    s16x8 alo = __builtin_bit_cast(s16x8, vl);                                   \
    u32 ob = ((u32)(ks * 64 + lq * 16)) ^ swz;                                   \
    _Pragma("unroll") for (int gg = 0; gg < 4; ++gg) {                           \
      s16x8 bh = *(const s16x8*)((const char*)lds_hi + (u32)(gg * 16 + lr) * 2048 + ob); \
      s16x8 bl = __builtin_bit_cast(s16x8, qb[BUF][ii][gg]);                     \
      acc[gg] = __builtin_amdgcn_mfma_f32_16x16x32_bf16(ahi, bh, acc[gg], 0, 0, 0); \
      acc[gg] = __builtin_amdgcn_mfma_f32_16x16x32_bf16(alo, bh, acc[gg], 0, 0, 0); \
      acc[gg] = __builtin_amdgcn_mfma_f32_16x16x32_bf16(ahi, bl, acc[gg], 0, 0, 0); \
    }                                                                            \
  }

  for (int t = 0; t < Tn; ++t) {
    const int pin = t & 1, pout = pin ^ 1;
    f32x4 acc[4];
#pragma unroll
    for (int gg = 0; gg < 4; ++gg)
      acc[gg] = (f32x4){bias[gg], bias[gg], bias[gg], bias[gg]};

    // ---- x-projection first (h-independent, compiler loads, drained here) ----
    const unsigned short* ipA = inp2 + ((size_t)(t * 8 + (g * 2 + wv)) * 10) * 512 + l * 8;
#pragma unroll
    for (int ks = 0; ks < 10; ++ks) {
      s16x8 a = *(const s16x8*)(ipA + ks * 512);
#pragma unroll
      for (int gg = 0; gg < 4; ++gg) {
        s16x8 b = *(const s16x8*)(wihB + (size_t)gg * 327680 + ks * 512);
        acc[gg] = __builtin_amdgcn_mfma_f32_16x16x32_bf16(a, b, acc[gg], 0, 0, 0);
      }
    }

    // ---- wait for h(t): one flag load per lane + ballot over all 64 blocks ----
    if (t) {
      u32 spins = 0;
      for (;;) {
        u32 f = LDQ32(fg + l);
        if (__ballot(f >= (u32)t) == ~0ull) break;
        __builtin_amdgcn_s_sleep(2);
        if (++spins > 200000u) break;  // watchdog: dead unless deadlock
      }
    }

    // ---- recurrent K=1024: 8 chunks, 2-deep asm prefetch, counted vmcnt ----
    const u32* hbase = h_pk + ((size_t)pin * Bn + b0w + lr) * Hn + lq * 8;
    ISSUE_A(0, 0) ISSUE_BL(0, 0) ISSUE_A(1, 1) ISSUE_BL(1, 1)
    WAITV24; BODY_(0, 0) ISSUE_A(0, 2) ISSUE_BL(0, 2)
    WAITV24; BODY_(1, 1) ISSUE_A(1, 3) ISSUE_BL(1, 3)
    WAITV24; BODY_(0, 2) ISSUE_A(0, 4) ISSUE_BL(0, 4)
    WAITV24; BODY_(1, 3) ISSUE_A(1, 5) ISSUE_BL(1, 5)
    WAITV24; BODY_(0, 4) ISSUE_A(0, 6) ISSUE_BL(0, 6)
    WAITV24; BODY_(1, 5) ISSUE_A(1, 7) ISSUE_BL(1, 7)
    WAITV24; BODY_(0, 6)
    WAITV0;  BODY_(1, 7)

    // ---- gates + state update (all 4 gates in-lane; no cross-lane mixing) ----
#pragma unroll
    for (int r = 0; r < 4; ++r) {
      float i_ = sigmoidf_(acc[0][r]);
      float f_ = sigmoidf_(acc[1][r]);
      float g_ = tanhf_(acc[2][r]);
      float o_ = sigmoidf_(acc[3][r]);
      float cn = f_ * creg[r] + i_ * g_;
      creg[r] = cn;
      float h = o_ * tanhf_(cn);
      unsigned short hh = f2bf(h);
      unsigned short hl = f2bf(h - bf2f(hh));
      int b = b0w + lq * 4 + r;
      ST32(h_pk + ((size_t)pout * Bn + b) * Hn + u0 + lr, (u32)hh | ((u32)hl << 16));
      if (t == tsr[r]) hsel[(size_t)b * Hn + u0 + lr] = pfr[r] ? 0.f : h;
    }

    // ---- arrival: drain stores(+loads), LDS-count both waves, publish flag ----
    asm volatile("s_waitcnt vmcnt(0)" ::: "memory");
    if (l == 0) {
      u32 old = atomicAdd(&cnt, 1u);           // LDS atomic, lgkm-ordered
      if (old == (u32)(2 * t + 1)) ST32(flags + (g << 6) + j, (u32)(t + 1));
    }
  }
#undef ISSUE_A
#undef ISSUE_BL
#undef BODY_
}

// ---------------- K5: out[b][o] = hsel[b]·W_out[o] + b_out[o] ----------------
__global__ void head_kernel(const float* __restrict__ hsel, const float* __restrict__ Wout,
                            const float* __restrict__ bout, float* __restrict__ out) {
  int b = blockIdx.x;
  int l = threadIdx.x;  // 64 threads
  float s0 = 0.f, s1 = 0.f, s2 = 0.f;
  for (int jj = l; jj < Hn; jj += 64) {
    float h = hsel[(size_t)b * Hn + jj];
    s0 += h * Wout[jj];
    s1 += h * Wout[Hn + jj];
    s2 += h * Wout[2 * Hn + jj];
  }
#pragma unroll
  for (int m = 32; m; m >>= 1) {
    s0 += __shfl_xor(s0, m);
    s1 += __shfl_xor(s1, m);
    s2 += __shfl_xor(s2, m);
  }
  if (l == 0) {
    out[b * 3 + 0] = s0 + bout[0];
    out[b * 3 + 1] = s1 + bout[1];
    out[b * 3 + 2] = s2 + bout[2];
  }
}

extern "C" void kernel_launch(void* const* d_in, const int* in_sizes, int n_in,
                              void* d_out, int out_size, void* d_ws, size_t ws_size,
                              hipStream_t stream) {
  const int* x = (const int*)d_in[0];
  const float* embed = (const float*)d_in[1];
  const float* Wih = (const float*)d_in[2];
  const float* Whh = (const float*)d_in[3];
  const float* bih = (const float*)d_in[4];
  const float* bhh = (const float*)d_in[5];
  const float* Wout = (const float*)d_in[6];
  const float* bout = (const float*)d_in[7];
  float* out = (float*)d_out;

  // ws layout
  const size_t INP2_BYTES = (size_t)256 * 8 * 10 * 512 * 2;   // 20,971,520
  const size_t WIH2_BYTES = (size_t)256 * 10 * 512 * 2;       //  2,621,440
  const size_t WLO2_BYTES = (size_t)256 * 32 * 512 * 2;       //  8,388,608
  const size_t HPK_BYTES = (size_t)2 * Bn * Hn * 4;           //  1,048,576
  const size_t HSEL_BYTES = (size_t)Bn * Hn * 4;              //    524,288
  char* p = (char*)d_ws;
  unsigned short* inp2 = (unsigned short*)p;            p += INP2_BYTES;
  unsigned short* wih2 = (unsigned short*)p;            p += WIH2_BYTES;
  unsigned short* wlo2 = (unsigned short*)p;            p += WLO2_BYTES;
  u32* h_pk = (u32*)p;                                  p += HPK_BYTES;
  float* hsel = (float*)p;                              p += HSEL_BYTES;
  int* tstar = (int*)p;                                 p += 512;
  int* padflag = (int*)p;                               p += 512;
  u32* flags = (u32*)p;                                 p += 4 * 64 * 4;

  // per-launch init: h(0) = 0 (first h_pk buffer), flags = 0
  hipMemsetAsync(h_pk, 0, (size_t)Bn * Hn * 4, stream);
  hipMemsetAsync(flags, 0, 4 * 64 * 4, stream);

  prep_kernel<<<1, 128, 0, stream>>>(x, tstar, padflag);
  gather2_kernel<<<40960, 256, 0, stream>>>(x, embed, inp2);
  wih2_kernel<<<5120, 256, 0, stream>>>(Wih, wih2);
  wlo2_kernel<<<16384, 256, 0, stream>>>(Whh, wlo2);
  lstm_scan<<<256, 128, 0, stream>>>(Whh, wih2, wlo2, bih, bhh, inp2, tstar, padflag,
                                     h_pk, hsel, flags);
  head_kernel<<<Bn, 64, 0, stream>>>(hsel, Wout, bout, out);
}

// Round 6
// 3111.652 us; speedup vs baseline: 3.2971x; 3.2971x over previous
//
#include <hip/hip_runtime.h>
#include <stdint.h>

#define Bn 128
#define Tn 256
#define En 300
#define EPn 320          // E padded to multiple of 32 (MFMA K)
#define Hn 1024
#define PADIDX 1
#define NBLK 256         // 2 groups x 128 col-blocks
#define NROT 16          // h buffer rotation depth (fresh address per step)

typedef short s16x8 __attribute__((ext_vector_type(8)));
typedef float f32x4 __attribute__((ext_vector_type(4)));
typedef unsigned int u32;
typedef u32 u32x4 __attribute__((ext_vector_type(4)));

#define LDQ32(p) __hip_atomic_load((p), __ATOMIC_RELAXED, __HIP_MEMORY_SCOPE_SYSTEM)
#define ST32(p, v) __hip_atomic_store((p), (v), __ATOMIC_RELAXED, __HIP_MEMORY_SCOPE_SYSTEM)

__device__ __forceinline__ unsigned short f2bf(float f) {
  u32 u = __builtin_bit_cast(u32, f);
  u32 r = (u + 0x7fffu + ((u >> 16) & 1u)) >> 16;  // RNE
  return (unsigned short)r;
}
__device__ __forceinline__ float bf2f(unsigned short h) {
  u32 u = ((u32)h) << 16;
  return __builtin_bit_cast(float, u);
}
__device__ __forceinline__ float sigmoidf_(float x) { return 1.f / (1.f + __expf(-x)); }
__device__ __forceinline__ float tanhf_(float x) { return 1.f - 2.f / (__expf(2.f * x) + 1.f); }

// h load: sc0 only -> bypass L1, CACHE IN XCD L2 (amortized across co-XCD blocks).
// Result NOT valid until manual s_waitcnt.
__device__ __forceinline__ u32x4 ldg_sc0_x4(const u32* p) {
  u32x4 r;
  asm volatile("global_load_dwordx4 %0, %1, off sc0" : "=v"(r) : "v"(p));
  return r;
}
#define WAITV8 do { asm volatile("s_waitcnt vmcnt(8)" ::: "memory"); \
                    __builtin_amdgcn_sched_barrier(0); } while (0)
#define WAITV0 do { asm volatile("s_waitcnt vmcnt(0)" ::: "memory");  \
                    __builtin_amdgcn_sched_barrier(0); } while (0)

// lane holds gate `gate` value v for its (b,unit); recover all 4 gates via shfl
__device__ __forceinline__ float gate_update(float pre, float& c, int gate) {
  float v = (gate == 2) ? tanhf_(pre) : sigmoidf_(pre);
  float vB = __shfl_xor(v, 4);
  float vC = __shfl_xor(v, 8);
  float vD = __shfl_xor(vB, 8);
  float i_ = (gate & 2) ? ((gate & 1) ? vD : vC) : ((gate & 1) ? vB : v);
  float f_ = (gate & 2) ? ((gate & 1) ? vC : vD) : ((gate & 1) ? v : vB);
  float g_ = (gate & 2) ? ((gate & 1) ? vB : v) : ((gate & 1) ? vD : vC);
  float o_ = (gate & 2) ? ((gate & 1) ? v : vB) : ((gate & 1) ? vC : vD);
  float cn = f_ * c + i_ * g_;
  c = cn;
  return o_ * tanhf_(cn);
}

// ---------------- K0: lengths -> tstar / padflag ----------------
__global__ void prep_kernel(const int* __restrict__ x, int* __restrict__ tstar,
                            int* __restrict__ padflag) {
  int b = threadIdx.x;
  if (b < Bn) {
    int len = 0;
    for (int t = 0; t < Tn; ++t) len += (x[b * Tn + t] != PADIDX) ? 1 : 0;
    int ts = (len > 0) ? (len - 1) : (Tn - 1);  // jax wraps index -1
    tstar[b] = ts;
    padflag[b] = (x[b * Tn + ts] == PADIDX) ? 1 : 0;
  }
}

// ---------------- K1: inp[t][b][k] = bf16(embed[x[b,t]][k]), k>=300 -> 0 ----
__global__ void gather_kernel(const int* __restrict__ x, const float* __restrict__ embed,
                              unsigned short* __restrict__ inp) {
  int idx = blockIdx.x * 256 + threadIdx.x;   // total = Tn*Bn*EPn
  int k = idx % EPn;
  int rem = idx / EPn;          // t*Bn + b
  int b = rem & (Bn - 1);
  int t = rem >> 7;
  int tok = x[b * Tn + t];
  float v = (k < En) ? embed[(size_t)tok * En + k] : 0.f;
  inp[idx] = f2bf(v);
}

// ---------------- K1b: W_ih -> bf16, K padded to 320 ----------------
__global__ void wihcvt_kernel(const float* __restrict__ Wih, unsigned short* __restrict__ wih_bf) {
  int idx = blockIdx.x * 256 + threadIdx.x;   // total = 4096*EPn
  int k = idx % EPn;
  int g = idx / EPn;
  float v = (k < En) ? Wih[(size_t)g * En + k] : 0.f;
  wih_bf[idx] = f2bf(v);
}

// ---------------- K2: persistent LSTM scan ----------------
// 256 blocks x 256 thr (4 waves). group = bid>>7 (64 batches); 128 col-blocks/group,
// each 8 hidden units (32 gate cols). W_hh hi/lo in 128 KB LDS (R4-proven).
// h: packed u32 (bf16 hi | lo<<16), 16-buffer rotation; stores sc0sc1 (write-through
// to L3, never dirty in L2), loads sc0 (L1-bypass, L2-FILL -> co-XCD amortization).
// Staleness: fresh address per step + fence(acquire,agent) every 8 steps kills any
// cached copy long before its address is reused at t+16.
// Sync: per-block monotone flag; all waves poll 128 flags (2 loads + ballot).
__global__ __launch_bounds__(256, 1) void lstm_scan(
    const float* __restrict__ Whh, const unsigned short* __restrict__ wih_bf,
    const float* __restrict__ bih, const float* __restrict__ bhh,
    const unsigned short* __restrict__ inp, const int* __restrict__ tstar,
    const int* __restrict__ padflag, u32* __restrict__ h_pk,
    float* __restrict__ hsel, u32* __restrict__ flags) {
  __shared__ unsigned short lds_hi[32 * Hn];   // 64 KB, XOR-swizzled rows
  __shared__ unsigned short lds_lo[32 * Hn];   // 64 KB

  const int bid = blockIdx.x;
  const int group = bid >> 7;              // 0: batches 0-63, 1: batches 64-127
  const int cb = bid & 127;                // col-block within group
  const int u0 = cb * 8;                   // 8 hidden units per block
  const int tid = threadIdx.x;

  // --- convert W_hh slice into LDS hi/lo (row c = ct*16 + gate*4 + usub) ---
  for (int i = tid; i < 32 * Hn; i += 256) {
    int c = i >> 10, k = i & (Hn - 1);
    int grow = ((c >> 2) & 3) * Hn + u0 + ((c >> 4) << 2) + (c & 3);
    float w = Whh[(size_t)grow * Hn + k];
    unsigned short hi = f2bf(w);
    unsigned short lo = f2bf(w - bf2f(hi));
    u32 byte = ((u32)(c * 2048 + k * 2)) ^ (((u32)(c & 7)) << 4);
    lds_hi[byte >> 1] = hi;
    lds_lo[byte >> 1] = lo;
  }
  __syncthreads();

  const int wv = tid >> 6, l = tid & 63;
  const int lr = l & 15;                    // A-row (batch) / D-col in tile
  const int lq = l >> 4;                    // quadrant
  const int usub = lr & 3, gate = lr >> 2;
  const int b0w = group * 64 + wv * 16;     // this wave's 16 batch rows
  const u32 wswz = ((u32)(lr & 7)) << 4;
  const int col0 = gate * Hn + u0 + usub;   // ct=0 gate column; ct=1 is col0+4
  const float bias0 = bih[col0] + bhh[col0];
  const float bias1 = bih[col0 + 4] + bhh[col0 + 4];
  u32* const fg = flags + (group << 7);     // group's 128 per-block flags

  int tsr[4], pfr[4];
#pragma unroll
  for (int r = 0; r < 4; ++r) {
    int b = b0w + lq * 4 + r;
    tsr[r] = tstar[b];
    pfr[r] = padflag[b];
  }
  float creg0[4] = {0.f, 0.f, 0.f, 0.f};
  float creg1[4] = {0.f, 0.f, 0.f, 0.f};

  const char* base_hi = (const char*)lds_hi;
  const char* base_lo = (const char*)lds_lo;

  u32x4 qa[2][4][2];  // h prefetch: 2 chunks x 4 ks x 32B

#define ISSUE_A(BUF, C)                                                          \
  _Pragma("unroll") for (int ii = 0; ii < 4; ++ii) {                             \
    const u32* p = hbase + ((C) * 4 + ii) * 32;                                  \
    qa[BUF][ii][0] = ldg_sc0_x4(p);                                              \
    qa[BUF][ii][1] = ldg_sc0_x4(p + 4);                                          \
  }
#define BODY_(BUF, C)                                                            \
  _Pragma("unroll") for (int ii = 0; ii < 4; ++ii) {                             \
    int ks = (C) * 4 + ii;                                                       \
    u32x4 q0 = qa[BUF][ii][0], q1 = qa[BUF][ii][1];                              \
    u32x4 vh, vl;                                                                \
    vh[0] = __builtin_amdgcn_perm(q0[1], q0[0], 0x05040100u);                    \
    vh[1] = __builtin_amdgcn_perm(q0[3], q0[2], 0x05040100u);                    \
    vh[2] = __builtin_amdgcn_perm(q1[1], q1[0], 0x05040100u);                    \
    vh[3] = __builtin_amdgcn_perm(q1[3], q1[2], 0x05040100u);                    \
    vl[0] = __builtin_amdgcn_perm(q0[1], q0[0], 0x07060302u);                    \
    vl[1] = __builtin_amdgcn_perm(q0[3], q0[2], 0x07060302u);                    \
    vl[2] = __builtin_amdgcn_perm(q1[1], q1[0], 0x07060302u);                    \
    vl[3] = __builtin_amdgcn_perm(q1[3], q1[2], 0x07060302u);                    \
    s16x8 ahi = __builtin_bit_cast(s16x8, vh);                                   \
    s16x8 alo = __builtin_bit_cast(s16x8, vl);                                   \
    u32 o0 = ((u32)(lr * 2048 + (ks * 32 + lq * 8) * 2)) ^ wswz;                 \
    u32 o1 = o0 + 32768;                                                         \
    s16x8 bh0 = *(const s16x8*)(base_hi + o0);                                   \
    s16x8 bl0 = *(const s16x8*)(base_lo + o0);                                   \
    s16x8 bh1 = *(const s16x8*)(base_hi + o1);                                   \
    s16x8 bl1 = *(const s16x8*)(base_lo + o1);                                   \
    acc0 = __builtin_amdgcn_mfma_f32_16x16x32_bf16(ahi, bh0, acc0, 0, 0, 0);     \
    acc1 = __builtin_amdgcn_mfma_f32_16x16x32_bf16(ahi, bh1, acc1, 0, 0, 0);     \
    acc0 = __builtin_amdgcn_mfma_f32_16x16x32_bf16(alo, bh0, acc0, 0, 0, 0);     \
    acc1 = __builtin_amdgcn_mfma_f32_16x16x32_bf16(alo, bh1, acc1, 0, 0, 0);     \
    acc0 = __builtin_amdgcn_mfma_f32_16x16x32_bf16(ahi, bl0, acc0, 0, 0, 0);     \
    acc1 = __builtin_amdgcn_mfma_f32_16x16x32_bf16(ahi, bl1, acc1, 0, 0, 0);     \
  }

  for (int t = 0; t < Tn; ++t) {
    f32x4 acc0 = {bias0, bias0, bias0, bias0};
    f32x4 acc1 = {bias1, bias1, bias1, bias1};

    // ---- x-projection FIRST (h-independent): overlaps the flag wait ----
    const unsigned short* ip = inp + ((size_t)t * Bn + b0w + lr) * EPn + lq * 8;
    const unsigned short* wp0 = wih_bf + (size_t)col0 * EPn + lq * 8;
#pragma unroll
    for (int ks = 0; ks < EPn / 32; ++ks) {
      s16x8 a = *(const s16x8*)(ip + ks * 32);
      s16x8 b0 = *(const s16x8*)(wp0 + ks * 32);
      s16x8 b1 = *(const s16x8*)(wp0 + 4 * EPn + ks * 32);
      acc0 = __builtin_amdgcn_mfma_f32_16x16x32_bf16(a, b0, acc0, 0, 0, 0);
      acc1 = __builtin_amdgcn_mfma_f32_16x16x32_bf16(a, b1, acc1, 0, 0, 0);
    }

    // ---- wait for all 128 blocks of my group to have published h(t) ----
    if (t) {
      u32 spins = 0;
      for (;;) {
        u32 f0 = LDQ32(fg + l);
        u32 f1 = LDQ32(fg + 64 + l);
        if (__ballot((f0 >= (u32)t) & (f1 >= (u32)t)) == ~0ull) break;
        __builtin_amdgcn_s_sleep(2);
        if (++spins > 400000u) break;  // watchdog: dead unless deadlock
      }
    }

    // ---- recurrent K=1024: 8 chunks, 2-deep prefetch, counted vmcnt ----
    const u32* hbase = h_pk + (size_t)(t & (NROT - 1)) * (Bn * Hn) +
                       (size_t)(b0w + lr) * Hn + lq * 8;
    ISSUE_A(0, 0) ISSUE_A(1, 1)
    WAITV8; BODY_(0, 0) ISSUE_A(0, 2)
    WAITV8; BODY_(1, 1) ISSUE_A(1, 3)
    WAITV8; BODY_(0, 2) ISSUE_A(0, 4)
    WAITV8; BODY_(1, 3) ISSUE_A(1, 5)
    WAITV8; BODY_(0, 4) ISSUE_A(0, 6)
    WAITV8; BODY_(1, 5) ISSUE_A(1, 7)
    WAITV8; BODY_(0, 6)
    WAITV0; BODY_(1, 7)

    // ---- gates + state update (both col-tiles) ----
    u32* const hout = h_pk + (size_t)((t + 1) & (NROT - 1)) * (Bn * Hn);
#pragma unroll
    for (int r = 0; r < 4; ++r) {
      float h0 = gate_update(acc0[r], creg0[r], gate);
      float h1 = gate_update(acc1[r], creg1[r], gate);
      unsigned short h0h = f2bf(h0);
      unsigned short h0l = f2bf(h0 - bf2f(h0h));
      unsigned short h1h = f2bf(h1);
      unsigned short h1l = f2bf(h1 - bf2f(h1h));
      if (gate == 0) {
        int b = b0w + lq * 4 + r;
        u32* rowp = hout + (size_t)b * Hn;
        ST32(rowp + u0 + usub, (u32)h0h | ((u32)h0l << 16));
        ST32(rowp + u0 + usub + 4, (u32)h1h | ((u32)h1l << 16));
        if (t == tsr[r]) {
          hsel[(size_t)b * Hn + u0 + usub] = pfr[r] ? 0.f : h0;
          hsel[(size_t)b * Hn + u0 + usub + 4] = pfr[r] ? 0.f : h1;
        }
      }
    }

    // ---- arrival: block barrier drains all waves' vmcnt, then publish flag ----
    __syncthreads();
    if (tid == 0) ST32(fg + cb, (u32)(t + 1));
    // every 8 steps: invalidate local L2/L1 copies of h lines (cheap, amortized);
    // guarantees no stale line survives to the address's reuse at t+16
    if ((t & 7) == 7) __builtin_amdgcn_fence(__ATOMIC_ACQUIRE, "agent");
  }
#undef ISSUE_A
#undef BODY_
}

// ---------------- K3: out[b][o] = hsel[b]·W_out[o] + b_out[o] ----------------
__global__ void head_kernel(const float* __restrict__ hsel, const float* __restrict__ Wout,
                            const float* __restrict__ bout, float* __restrict__ out) {
  int b = blockIdx.x;
  int l = threadIdx.x;  // 64 threads
  float s0 = 0.f, s1 = 0.f, s2 = 0.f;
  for (int j = l; j < Hn; j += 64) {
    float h = hsel[(size_t)b * Hn + j];
    s0 += h * Wout[j];
    s1 += h * Wout[Hn + j];
    s2 += h * Wout[2 * Hn + j];
  }
#pragma unroll
  for (int m = 32; m; m >>= 1) {
    s0 += __shfl_xor(s0, m);
    s1 += __shfl_xor(s1, m);
    s2 += __shfl_xor(s2, m);
  }
  if (l == 0) {
    out[b * 3 + 0] = s0 + bout[0];
    out[b * 3 + 1] = s1 + bout[1];
    out[b * 3 + 2] = s2 + bout[2];
  }
}

extern "C" void kernel_launch(void* const* d_in, const int* in_sizes, int n_in,
                              void* d_out, int out_size, void* d_ws, size_t ws_size,
                              hipStream_t stream) {
  const int* x = (const int*)d_in[0];
  const float* embed = (const float*)d_in[1];
  const float* Wih = (const float*)d_in[2];
  const float* Whh = (const float*)d_in[3];
  const float* bih = (const float*)d_in[4];
  const float* bhh = (const float*)d_in[5];
  const float* Wout = (const float*)d_in[6];
  const float* bout = (const float*)d_in[7];
  float* out = (float*)d_out;

  // ws layout
  const size_t INP_BYTES = (size_t)Tn * Bn * EPn * 2;        // 20,971,520
  const size_t WIH_BYTES = (size_t)4 * Hn * EPn * 2;         //  2,621,440
  const size_t HPK_BYTES = (size_t)NROT * Bn * Hn * 4;       //  8,388,608
  const size_t HSEL_BYTES = (size_t)Bn * Hn * 4;             //    524,288
  char* p = (char*)d_ws;
  unsigned short* inp = (unsigned short*)p;             p += INP_BYTES;
  unsigned short* wih_bf = (unsigned short*)p;          p += WIH_BYTES;
  u32* h_pk = (u32*)p;                                  p += HPK_BYTES;
  float* hsel = (float*)p;                              p += HSEL_BYTES;
  int* tstar = (int*)p;                                 p += 512;
  int* padflag = (int*)p;                               p += 512;
  u32* flags = (u32*)p;                                 p += 1024;

  // per-launch init: h(0) = 0 (rotation slot 0), flags = 0 (self-contained replay)
  hipMemsetAsync(h_pk, 0, (size_t)Bn * Hn * 4, stream);
  hipMemsetAsync(flags, 0, 1024, stream);

  prep_kernel<<<1, 128, 0, stream>>>(x, tstar, padflag);
  gather_kernel<<<(Tn * Bn * EPn) / 256, 256, 0, stream>>>(x, embed, inp);
  wihcvt_kernel<<<(4 * Hn * EPn) / 256, 256, 0, stream>>>(Wih, wih_bf);
  lstm_scan<<<NBLK, 256, 0, stream>>>(Whh, wih_bf, bih, bhh, inp, tstar, padflag,
                                      h_pk, hsel, flags);
  head_kernel<<<Bn, 64, 0, stream>>>(hsel, Wout, bout, out);
}